// Round 2
// baseline (670.271 us; speedup 1.0000x reference)
//
#include <hip/hip_runtime.h>
#include <math.h>

#define N_ 16
#define K_ 3
#define C_ 256
#define T_ 128
#define V_ 50
#define H_ 4
#define HD_ 64
#define TV (T_*V_)          // 6400
#define NEG_SLOPE 0.2f
#define BN_EPS 1e-5f

// ---------------------------------------------------------------------------
// K1: xs[n,c,t,v] = sum_k x[n,k,c,t,v]  (written into d_out as staging)
//     xbar[n,c,v] = mean_{k,t} x[n,k,c,t,v]
// grid = N*C blocks, 256 threads
// ---------------------------------------------------------------------------
__global__ void __launch_bounds__(256) k1_sumk(const float* __restrict__ x,
                                               float* __restrict__ xs,
                                               float* __restrict__ xbar) {
    int b = blockIdx.x;              // n*C_ + c
    int n = b / C_;
    int c = b % C_;
    const float* x0 = x + ((size_t)n * K_ * C_ + c) * TV;
    const float* x1 = x0 + (size_t)C_ * TV;
    const float* x2 = x1 + (size_t)C_ * TV;
    float* o = xs + (size_t)b * TV;

    __shared__ float sv[V_];
    if (threadIdx.x < V_) sv[threadIdx.x] = 0.f;
    __syncthreads();

    for (int i = threadIdx.x; i < TV; i += 256) {
        float s = x0[i] + x1[i] + x2[i];
        o[i] = s;
        atomicAdd(&sv[i % V_], s);
    }
    __syncthreads();
    if (threadIdx.x < V_)
        xbar[(size_t)b * V_ + threadIdx.x] = sv[threadIdx.x] * (1.f / (float)(K_ * T_));
}

// ---------------------------------------------------------------------------
// K2: fp[d,v] = sum_c W_w[d,c]*xbar[n,c,v] + W_b[d]
//     scores[v,w] = sum_d lrelu(fp[d,v]+fp[d,w]) * att[d];  mask; softmax rows
//     -> attn[n,v,w]
// grid = N blocks, 1024 threads
// ---------------------------------------------------------------------------
__global__ void __launch_bounds__(1024) k2_attn(const float* __restrict__ xbar,
                                                const float* __restrict__ Ww,
                                                const float* __restrict__ Wb,
                                                const float* __restrict__ att,
                                                const int* __restrict__ mask,
                                                float* __restrict__ attn) {
    int n = blockIdx.x;
    __shared__ float buf[C_ * 52];    // xbar staged, then reused for fp
    __shared__ float att_s[C_];
    __shared__ float sc[V_ * V_];
    int tid = threadIdx.x;

    // stage xbar[n] (pad cols 50..51 with 0)
    for (int i = tid; i < C_ * 52; i += 1024) {
        int c = i / 52, v = i % 52;
        buf[i] = (v < V_) ? xbar[((size_t)n * C_ + c) * V_ + v] : 0.f;
    }
    if (tid < C_) att_s[tid] = att[tid];
    __syncthreads();

    // fp = W @ xbar + b ; thread = (d, quarter of v)
    int d = tid >> 2, q = tid & 3;
    int v0 = q * 13;                  // 0,13,26,39 ; each handles 13 (guarded)
    float acc[13];
    {
        float bias = Wb[d];
        #pragma unroll
        for (int j = 0; j < 13; ++j) acc[j] = bias;
        const float* wrow = Ww + (size_t)d * C_;
        for (int c = 0; c < C_; ++c) {
            float wv = wrow[c];
            const float* xr = &buf[c * 52 + v0];
            #pragma unroll
            for (int j = 0; j < 13; ++j) acc[j] += wv * xr[j];
        }
    }
    __syncthreads();                  // everyone done reading xbar from buf
    #pragma unroll
    for (int j = 0; j < 13; ++j) {
        int v = v0 + j;
        if (v < V_) buf[d * 52 + v] = acc[j];
    }
    __syncthreads();

    // scores + mask
    for (int p = tid; p < V_ * V_; p += 1024) {
        int v = p / V_, w = p % V_;
        float s = 0.f;
        for (int dd = 0; dd < C_; ++dd) {
            float t = buf[dd * 52 + v] + buf[dd * 52 + w];
            t = (t >= 0.f) ? t : NEG_SLOPE * t;
            s += t * att_s[dd];
        }
        sc[p] = (mask[p] == 0) ? -1e9f : s;
    }
    __syncthreads();

    // row softmax (one thread per row; tiny)
    if (tid < V_) {
        float* row = &sc[tid * V_];
        float m = row[0];
        for (int w = 1; w < V_; ++w) m = fmaxf(m, row[w]);
        float sum = 0.f;
        float e[V_];
        #pragma unroll
        for (int w = 0; w < V_; ++w) { e[w] = __expf(row[w] - m); sum += e[w]; }
        float inv = 1.f / sum;
        float* o = attn + (size_t)n * V_ * V_ + tid * V_;
        #pragma unroll
        for (int w = 0; w < V_; ++w) o[w] = e[w] * inv;
    }
}

// ---------------------------------------------------------------------------
// K3: out[n,c,t,w] = sum_v xs[n,c,t,v] * attn[n,v,w]   (in-place on d_out)
//     + per-channel sum / sumsq partials for BN
// grid = N*C blocks, 256 threads (4 waves; lane=w, wave owns 32 t's)
// ---------------------------------------------------------------------------
__global__ void __launch_bounds__(256) k3_agg(float* __restrict__ io,
                                              const float* __restrict__ attn,
                                              float* __restrict__ bnsum,
                                              float* __restrict__ bnsumsq) {
    int b = blockIdx.x;              // n*C_ + c
    int n = b / C_;
    int c = b % C_;
    __shared__ float xs_s[T_ * 52];
    __shared__ float rs[8];
    float* base = io + (size_t)b * TV;
    int tid = threadIdx.x;

    for (int i = tid; i < TV; i += 256)
        xs_s[(i / V_) * 52 + (i % V_)] = base[i];
    __syncthreads();

    int lane = tid & 63, wave = tid >> 6;
    int w = (lane < V_) ? lane : 0;
    const float* ag = attn + (size_t)n * V_ * V_;
    float a[V_];
    #pragma unroll
    for (int v = 0; v < V_; ++v) a[v] = ag[v * V_ + w];

    float ls = 0.f, lss = 0.f;
    for (int j = 0; j < T_ / 4; ++j) {
        int t = wave * (T_ / 4) + j;
        const float* xr = &xs_s[t * 52];
        float acc = 0.f;
        #pragma unroll
        for (int v = 0; v < V_; ++v) acc += xr[v] * a[v];
        if (lane < V_) {
            base[t * V_ + lane] = acc;
            ls += acc;
            lss += acc * acc;
        }
    }

    // reduce ls/lss across block, one atomic pair per block
    #pragma unroll
    for (int off = 32; off > 0; off >>= 1) {
        ls  += __shfl_down(ls,  off, 64);
        lss += __shfl_down(lss, off, 64);
    }
    if (lane == 0) { rs[wave] = ls; rs[4 + wave] = lss; }
    __syncthreads();
    if (tid == 0) {
        float s  = rs[0] + rs[1] + rs[2] + rs[3];
        float ss = rs[4] + rs[5] + rs[6] + rs[7];
        atomicAdd(&bnsum[c],   s);
        atomicAdd(&bnsumsq[c], ss);
    }
}

// ---------------------------------------------------------------------------
// K4: per-channel scale/shift from BN stats
// ---------------------------------------------------------------------------
__global__ void k4_stats(const float* __restrict__ bnsum, const float* __restrict__ bnsumsq,
                         const float* __restrict__ gamma, const float* __restrict__ beta,
                         float* __restrict__ scale, float* __restrict__ shift) {
    int c = threadIdx.x;
    const float M = (float)(N_ * T_ * V_);
    float mean = bnsum[c] / M;
    float var  = bnsumsq[c] / M - mean * mean;
    float inv  = rsqrtf(var + BN_EPS);
    float s    = gamma[c] * inv;
    scale[c] = s;
    shift[c] = beta[c] - mean * s;
}

// ---------------------------------------------------------------------------
// K5: out = relu(out*scale[c] + shift[c])  (in-place, float4)
// ---------------------------------------------------------------------------
__global__ void __launch_bounds__(256) k5_bn(float* __restrict__ io,
                                             const float* __restrict__ scale,
                                             const float* __restrict__ shift) {
    size_t idx4 = (size_t)blockIdx.x * 256 + threadIdx.x;
    const size_t tot4 = (size_t)N_ * C_ * TV / 4;
    if (idx4 >= tot4) return;
    int c = (int)((idx4 / (TV / 4)) % C_);
    float s = scale[c], b = shift[c];
    float4 v = ((float4*)io)[idx4];
    v.x = fmaxf(v.x * s + b, 0.f);
    v.y = fmaxf(v.y * s + b, 0.f);
    v.z = fmaxf(v.z * s + b, 0.f);
    v.w = fmaxf(v.w * s + b, 0.f);
    ((float4*)io)[idx4] = v;
}

// ---------------------------------------------------------------------------
extern "C" void kernel_launch(void* const* d_in, const int* in_sizes, int n_in,
                              void* d_out, int out_size, void* d_ws, size_t ws_size,
                              hipStream_t stream) {
    const float* x     = (const float*)d_in[0];
    const float* Ww    = (const float*)d_in[1];
    const float* Wb    = (const float*)d_in[2];
    const float* att   = (const float*)d_in[3];
    const float* gamma = (const float*)d_in[4];
    const float* beta  = (const float*)d_in[5];
    const int*   mask  = (const int*)d_in[6];
    float* out = (float*)d_out;
    float* ws  = (float*)d_ws;

    float* xbar    = ws;                 // N*C*V   = 204800
    float* attn    = ws + 204800;        // N*V*V   = 40000
    float* bnsum   = ws + 244800;        // 256
    float* bnsumsq = ws + 245056;        // 256
    float* scale   = ws + 245312;        // 256
    float* shift   = ws + 245568;        // 256

    hipMemsetAsync(bnsum, 0, 512 * sizeof(float), stream);

    k1_sumk<<<N_ * C_, 256, 0, stream>>>(x, out, xbar);
    k2_attn<<<N_, 1024, 0, stream>>>(xbar, Ww, Wb, att, mask, attn);
    k3_agg<<<N_ * C_, 256, 0, stream>>>(out, attn, bnsum, bnsumsq);
    k4_stats<<<1, 256, 0, stream>>>(bnsum, bnsumsq, gamma, beta, scale, shift);
    k5_bn<<<(N_ * C_ * TV / 4 + 255) / 256, 256, 0, stream>>>(out, scale, shift);
}